// Round 1
// baseline (3483.040 us; speedup 1.0000x reference)
//
#include <hip/hip_runtime.h>

// Neural HMM forward-algorithm NLL.
// K=128 states, V=50257 vocab, D=H=128, B=64, T=2048.
//
// Pipeline (all fp32, linear-space scaled forward algorithm):
//  K1: E[v][k] = exp(tag[k]·word[v] + bias[v])   (UNNORMALIZED; logits ~ +-0.03
//      so no max-subtraction needed), plus per-block partial Z_k sums.
//  K2: A2[i][j] = softmax_j(W q + b)[i][j] / Z_j  (emission normalizer folded
//      into transition columns), piZ[j] = softmax(init)[j] / Z_j.
//  K3: per-batch recursion a'_j = (sum_i a_i A2_ij) * E[tok]_j with sum-rescale
//      every 4 steps; LL_b = sum log(scales) + log(sum_j a_T).
//  K4: out = -sum_b LL_b.

#define KK 128
#define TT 2048
#define BB 64

__device__ __forceinline__ float wave_sum64(float v) {
#pragma unroll
  for (int m = 32; m; m >>= 1) v += __shfl_xor(v, m, 64);
  return v;
}
__device__ __forceinline__ float wave_max64(float v) {
#pragma unroll
  for (int m = 32; m; m >>= 1) v = fmaxf(v, __shfl_xor(v, m, 64));
  return v;
}

// ---------------- K1: emission table E (V x K) + partial Z ----------------
// grid: ceil(V/128) blocks x 128 threads. Thread k holds tag row k in VGPRs;
// word rows broadcast from LDS (uniform-address ds_read_b128, conflict-free).
__global__ __launch_bounds__(128, 1)
void k_emis(const float* __restrict__ tag, const float* __restrict__ word,
            const float* __restrict__ bias, float* __restrict__ E,
            float* __restrict__ partialZ, int V) {
  __shared__ float4 wtile[128 * 32];  // 64 KB: 128 vocab rows x 128 d
  __shared__ float btile[128];
  const int tid = threadIdx.x;
  const int v0 = blockIdx.x * 128;

  // stage word tile, coalesced float4
  const float4* w4 = (const float4*)word;
  const int maxi = V * 32 - 1;
#pragma unroll
  for (int it = 0; it < 32; ++it) {
    int idx = it * 128 + tid;
    int g = v0 * 32 + idx;
    wtile[idx] = w4[min(g, maxi)];
  }
  btile[tid] = (v0 + tid < V) ? bias[v0 + tid] : 0.f;

  // tag row k=tid into registers
  float treg[128];
  const float4* t4 = (const float4*)(tag + (size_t)tid * 128);
#pragma unroll
  for (int c = 0; c < 32; ++c) {
    float4 x = t4[c];
    treg[4 * c + 0] = x.x; treg[4 * c + 1] = x.y;
    treg[4 * c + 2] = x.z; treg[4 * c + 3] = x.w;
  }
  __syncthreads();

  float zp = 0.f;
  for (int v = 0; v < 128; ++v) {
    if (v0 + v >= V) break;  // uniform
    const float4* row = &wtile[v * 32];
    float a0 = 0.f, a1 = 0.f, a2 = 0.f, a3 = 0.f;
#pragma unroll
    for (int c = 0; c < 32; ++c) {
      float4 pv = row[c];
      a0 = fmaf(pv.x, treg[4 * c + 0], a0);
      a1 = fmaf(pv.y, treg[4 * c + 1], a1);
      a2 = fmaf(pv.z, treg[4 * c + 2], a2);
      a3 = fmaf(pv.w, treg[4 * c + 3], a3);
    }
    float e = __expf((a0 + a1) + (a2 + a3) + btile[v]);
    E[(size_t)(v0 + v) * KK + tid] = e;
    zp += e;
  }
  partialZ[(size_t)blockIdx.x * KK + tid] = zp;  // deterministic (no atomics)
}

// ---------------- K2: transition matrix A2 (K x K) + piZ ----------------
__global__ __launch_bounds__(128)
void k_trans(const float* __restrict__ W, const float* __restrict__ q,
             const float* __restrict__ tb, const float* __restrict__ pZ,
             const float* __restrict__ initlog, float* __restrict__ A2,
             float* __restrict__ piZ, int nPart) {
  __shared__ float qs[KK];
  __shared__ float r0[2], r1[2];
  const int j = threadIdx.x, i = blockIdx.x;
  qs[j] = q[j];
  __syncthreads();

  const float4* w4 = (const float4*)(W + ((size_t)(i * KK + j)) * KK);
  const float4* q4 = (const float4*)qs;
  float a0 = 0.f, a1 = 0.f, a2 = 0.f, a3 = 0.f;
#pragma unroll
  for (int c = 0; c < KK / 4; ++c) {
    float4 wv = w4[c], qv = q4[c];
    a0 = fmaf(wv.x, qv.x, a0); a1 = fmaf(wv.y, qv.y, a1);
    a2 = fmaf(wv.z, qv.z, a2); a3 = fmaf(wv.w, qv.w, a3);
  }
  float logit = (a0 + a1) + (a2 + a3) + tb[i * KK + j];

  float m = wave_max64(logit);
  if ((j & 63) == 0) r0[j >> 6] = m;
  __syncthreads();
  m = fmaxf(r0[0], r0[1]);
  float e = __expf(logit - m);
  float s = wave_sum64(e);
  if ((j & 63) == 0) r1[j >> 6] = s;
  __syncthreads();
  s = r1[0] + r1[1];

  // Z_j: deterministic sum of per-block partials
  float Z = 0.f;
  for (int p = 0; p < nPart; ++p) Z += pZ[(size_t)p * KK + j];

  A2[i * KK + j] = e / (s * Z);

  if (i == 0) {
    float x = initlog[j];
    __syncthreads();
    float m2 = wave_max64(x);
    if ((j & 63) == 0) r0[j >> 6] = m2;
    __syncthreads();
    m2 = fmaxf(r0[0], r0[1]);
    float e2 = __expf(x - m2);
    float s2 = wave_sum64(e2);
    if ((j & 63) == 0) r1[j >> 6] = s2;
    __syncthreads();
    s2 = r1[0] + r1[1];
    piZ[j] = e2 / (s2 * Z);
  }
}

// ---------------- K3: forward recursion, one block per batch ----------------
// 128 threads (2 waves); thread j holds A2 column j in 128 VGPRs.
__global__ __launch_bounds__(128, 1)
void k_fwd(const int* __restrict__ toks, const float* __restrict__ E,
           const float* __restrict__ A2, const float* __restrict__ piZ,
           float* __restrict__ ll) {
  __shared__ float pb[2][KK];
  __shared__ int tk[TT];
  __shared__ float red[2];
  const int j = threadIdx.x;
  const int b = blockIdx.x;

  // stage this batch's tokens (8 KB)
  const int4* t4 = (const int4*)(toks + (size_t)b * TT);
  int4* l4 = (int4*)tk;
#pragma unroll
  for (int c = 0; c < TT / 4 / KK; ++c) l4[c * KK + j] = t4[c * KK + j];

  // A column j -> registers (coalesced per-i loads)
  float Areg[128];
#pragma unroll
  for (int i = 0; i < 128; ++i) Areg[i] = A2[i * KK + j];

  __syncthreads();

  float cur = piZ[j] * E[(size_t)tk[0] * KK + j];
  float eN  = E[(size_t)tk[1] * KK + j];   // prefetch t=1
  float eNN = E[(size_t)tk[2] * KK + j];   // prefetch t=2
  float Lacc = 0.f;

  for (int t = 1; t < TT; ++t) {
    const int buf = t & 1;
    pb[buf][j] = cur;
    __syncthreads();

    const float4* p4 = (const float4*)pb[buf];
    float a0 = 0.f, a1 = 0.f, a2 = 0.f, a3 = 0.f;
#pragma unroll
    for (int c = 0; c < 32; ++c) {
      float4 pv = p4[c];  // broadcast read, conflict-free
      a0 = fmaf(pv.x, Areg[4 * c + 0], a0);
      a1 = fmaf(pv.y, Areg[4 * c + 1], a1);
      a2 = fmaf(pv.z, Areg[4 * c + 2], a2);
      a3 = fmaf(pv.w, Areg[4 * c + 3], a3);
    }

    float e = eN;
    eN = eNN;
    int tn = tk[min(t + 2, TT - 1)];
    eNN = E[(size_t)tn * KK + j];  // prefetch 2 ahead (L3-resident table)

    cur = ((a0 + a1) + (a2 + a3)) * e;

    if ((t & 3) == 0) {  // rescale every 4 steps (range: shrink ~2e-5/step)
      float v = wave_sum64(cur);
      if ((j & 63) == 0) red[j >> 6] = v;
      __syncthreads();
      float tot = red[0] + red[1];
      Lacc += __logf(tot);
      cur /= tot;
    }
  }

  float v = wave_sum64(cur);
  if ((j & 63) == 0) red[j >> 6] = v;
  __syncthreads();
  float tot = red[0] + red[1];
  if (j == 0) ll[b] = Lacc + __logf(tot);
}

// ---------------- K4: final reduction ----------------
__global__ void k_final(const float* __restrict__ ll, float* __restrict__ out) {
  float v = ll[threadIdx.x];
  v = wave_sum64(v);
  if (threadIdx.x == 0) out[0] = -v;
}

extern "C" void kernel_launch(void* const* d_in, const int* in_sizes, int n_in,
                              void* d_out, int out_size, void* d_ws, size_t ws_size,
                              hipStream_t stream) {
  const int*   toks    = (const int*)d_in[0];
  const float* initlog = (const float*)d_in[1];
  const float* tag     = (const float*)d_in[2];
  const float* word    = (const float*)d_in[3];
  const float* bias    = (const float*)d_in[4];
  const float* q       = (const float*)d_in[5];
  const float* W       = (const float*)d_in[6];
  const float* tb      = (const float*)d_in[7];
  float* out = (float*)d_out;

  const int V = in_sizes[4];          // vocab size (word_bias length)
  const int nPart = (V + 127) / 128;

  float* ws  = (float*)d_ws;
  float* E   = ws;                               // V*K
  float* pZ  = E + (size_t)V * KK;               // nPart*K
  float* A2  = pZ + (size_t)nPart * KK;          // K*K
  float* piZ = A2 + KK * KK;                     // K
  float* ll  = piZ + KK;                         // B

  k_emis <<<nPart, 128, 0, stream>>>(tag, word, bias, E, pZ, V);
  k_trans<<<KK, 128, 0, stream>>>(W, q, tb, pZ, initlog, A2, piZ, nPart);
  k_fwd  <<<BB, 128, 0, stream>>>(toks, E, A2, piZ, ll);
  k_final<<<1, BB, 0, stream>>>(ll, out);
}

// Round 2
// 1592.354 us; speedup vs baseline: 2.1874x; 2.1874x over previous
//
#include <hip/hip_runtime.h>

// Neural HMM forward-algorithm NLL.
// K=128 states, V=50257 vocab, D=H=128, B=64, T=2048.
//
// Pipeline (all fp32, linear-space scaled forward algorithm):
//  K1: E[v][k] = exp(tag[k]·word[v] + bias[v])   (UNNORMALIZED; logits ~ +-0.03
//      so no max-subtraction needed), plus per-block partial Z_k sums.
//  K2: A2[i][j] = softmax_j(W q + b)[i][j] / Z_j  (emission normalizer folded
//      into transition columns), piZ[j] = softmax(init)[j] / Z_j.
//  K3: per-batch recursion a'_j = (sum_i a_i A2_ij) * E[tok]_j.
//      Range control: exact *2^64 every 4 steps (per-step shrink ~2e-5), true
//      sum-normalize every 64 steps; the 480 exact 2^64 factors are removed by
//      a compile-time 30720*ln2 constant.
//  K4: out = -sum_b ll[b].

#define KK 128
#define TT 2048
#define BB 64

__device__ __forceinline__ float wave_sum64(float v) {
#pragma unroll
  for (int m = 32; m; m >>= 1) v += __shfl_xor(v, m, 64);
  return v;
}
__device__ __forceinline__ float wave_max64(float v) {
#pragma unroll
  for (int m = 32; m; m >>= 1) v = fmaxf(v, __shfl_xor(v, m, 64));
  return v;
}

// ---------------- K1: emission table E (V x K) + partial Z ----------------
__global__ __launch_bounds__(128, 1)
void k_emis(const float* __restrict__ tag, const float* __restrict__ word,
            const float* __restrict__ bias, float* __restrict__ E,
            float* __restrict__ partialZ, int V) {
  __shared__ float4 wtile[128 * 32];  // 64 KB: 128 vocab rows x 128 d
  __shared__ float btile[128];
  const int tid = threadIdx.x;
  const int v0 = blockIdx.x * 128;

  const float4* w4 = (const float4*)word;
  const int maxi = V * 32 - 1;
#pragma unroll
  for (int it = 0; it < 32; ++it) {
    int idx = it * 128 + tid;
    int g = v0 * 32 + idx;
    wtile[idx] = w4[min(g, maxi)];
  }
  btile[tid] = (v0 + tid < V) ? bias[v0 + tid] : 0.f;

  float treg[128];
  const float4* t4 = (const float4*)(tag + (size_t)tid * 128);
#pragma unroll
  for (int c = 0; c < 32; ++c) {
    float4 x = t4[c];
    treg[4 * c + 0] = x.x; treg[4 * c + 1] = x.y;
    treg[4 * c + 2] = x.z; treg[4 * c + 3] = x.w;
  }
  __syncthreads();

  float zp = 0.f;
  for (int v = 0; v < 128; ++v) {
    if (v0 + v >= V) break;  // uniform
    const float4* row = &wtile[v * 32];
    float a0 = 0.f, a1 = 0.f, a2 = 0.f, a3 = 0.f;
#pragma unroll
    for (int c = 0; c < 32; ++c) {
      float4 pv = row[c];
      a0 = fmaf(pv.x, treg[4 * c + 0], a0);
      a1 = fmaf(pv.y, treg[4 * c + 1], a1);
      a2 = fmaf(pv.z, treg[4 * c + 2], a2);
      a3 = fmaf(pv.w, treg[4 * c + 3], a3);
    }
    float e = __expf((a0 + a1) + (a2 + a3) + btile[v]);
    E[(size_t)(v0 + v) * KK + tid] = e;
    zp += e;
  }
  partialZ[(size_t)blockIdx.x * KK + tid] = zp;  // deterministic (no atomics)
}

// ---------------- K2: transition matrix A2 (K x K) + piZ ----------------
__global__ __launch_bounds__(128)
void k_trans(const float* __restrict__ W, const float* __restrict__ q,
             const float* __restrict__ tb, const float* __restrict__ pZ,
             const float* __restrict__ initlog, float* __restrict__ A2,
             float* __restrict__ piZ, int nPart) {
  __shared__ float qs[KK];
  __shared__ float r0[2], r1[2];
  const int j = threadIdx.x, i = blockIdx.x;
  qs[j] = q[j];
  __syncthreads();

  const float4* w4 = (const float4*)(W + ((size_t)(i * KK + j)) * KK);
  const float4* q4 = (const float4*)qs;
  float a0 = 0.f, a1 = 0.f, a2 = 0.f, a3 = 0.f;
#pragma unroll
  for (int c = 0; c < KK / 4; ++c) {
    float4 wv = w4[c], qv = q4[c];
    a0 = fmaf(wv.x, qv.x, a0); a1 = fmaf(wv.y, qv.y, a1);
    a2 = fmaf(wv.z, qv.z, a2); a3 = fmaf(wv.w, qv.w, a3);
  }
  float logit = (a0 + a1) + (a2 + a3) + tb[i * KK + j];

  float m = wave_max64(logit);
  if ((j & 63) == 0) r0[j >> 6] = m;
  __syncthreads();
  m = fmaxf(r0[0], r0[1]);
  float e = __expf(logit - m);
  float s = wave_sum64(e);
  if ((j & 63) == 0) r1[j >> 6] = s;
  __syncthreads();
  s = r1[0] + r1[1];

  float Z = 0.f;
  for (int p = 0; p < nPart; ++p) Z += pZ[(size_t)p * KK + j];

  A2[i * KK + j] = e / (s * Z);

  if (i == 0) {
    float x = initlog[j];
    __syncthreads();
    float m2 = wave_max64(x);
    if ((j & 63) == 0) r0[j >> 6] = m2;
    __syncthreads();
    m2 = fmaxf(r0[0], r0[1]);
    float e2 = __expf(x - m2);
    float s2 = wave_sum64(e2);
    if ((j & 63) == 0) r1[j >> 6] = s2;
    __syncthreads();
    s2 = r1[0] + r1[1];
    piZ[j] = e2 / (s2 * Z);
  }
}

// ---------------- K3: forward recursion, one block per batch ----------------
// 128 threads (2 waves); thread j holds A2 column j in 128 NAMED scalar VGPRs
// (no array -> cannot go to scratch; asm pin prevents remat/sinking).

#define REP32(M) M(0) M(1) M(2) M(3) M(4) M(5) M(6) M(7) \
                 M(8) M(9) M(10) M(11) M(12) M(13) M(14) M(15) \
                 M(16) M(17) M(18) M(19) M(20) M(21) M(22) M(23) \
                 M(24) M(25) M(26) M(27) M(28) M(29) M(30) M(31)

#define DECLA(c) float A##c##_0, A##c##_1, A##c##_2, A##c##_3;
#define LOADA(c) A##c##_0 = Acol[(4*(c)+0)*KK]; A##c##_1 = Acol[(4*(c)+1)*KK]; \
                 A##c##_2 = Acol[(4*(c)+2)*KK]; A##c##_3 = Acol[(4*(c)+3)*KK];
#define PINA(c)  asm volatile("" : "+v"(A##c##_0), "+v"(A##c##_1), \
                                   "+v"(A##c##_2), "+v"(A##c##_3));
#define STEPC(c) { float4 pv = p4[c]; \
                   acc0 = fmaf(pv.x, A##c##_0, acc0); \
                   acc1 = fmaf(pv.y, A##c##_1, acc1); \
                   acc2 = fmaf(pv.z, A##c##_2, acc2); \
                   acc3 = fmaf(pv.w, A##c##_3, acc3); }

__global__ __launch_bounds__(128, 1)
void k_fwd(const int* __restrict__ toks, const float* __restrict__ E,
           const float* __restrict__ A2, const float* __restrict__ piZ,
           float* __restrict__ ll) {
  __shared__ float pb[2][KK];
  __shared__ int tk[TT];
  __shared__ float red[2];
  const int j = threadIdx.x;
  const int b = blockIdx.x;

  // stage this batch's tokens (8 KB)
  const int4* t4 = (const int4*)(toks + (size_t)b * TT);
  int4* l4 = (int4*)tk;
#pragma unroll
  for (int c = 0; c < TT / 4 / KK; ++c) l4[c * KK + j] = t4[c * KK + j];

  // A column j -> 128 named registers
  REP32(DECLA)
  const float* Acol = A2 + j;
  REP32(LOADA)
  REP32(PINA)

  __syncthreads();

  float cur = piZ[j] * E[(size_t)tk[0] * KK + j];
  float eA = E[(size_t)tk[1] * KK + j];
  float eB = E[(size_t)tk[2] * KK + j];
  float eC = E[(size_t)tk[3] * KK + j];
  float Lacc = 0.f;

  for (int t = 1; t < TT; ++t) {
    pb[t & 1][j] = cur;
    __syncthreads();

    const float4* p4 = (const float4*)pb[t & 1];
    float acc0 = 0.f, acc1 = 0.f, acc2 = 0.f, acc3 = 0.f;
    REP32(STEPC)

    float e = eA; eA = eB; eB = eC;
    int tn = tk[t + 3 < TT ? t + 3 : TT - 1];
    eC = E[(size_t)tn * KK + j];  // prefetch 3 ahead (L3-resident table)

    cur = ((acc0 + acc1) + (acc2 + acc3)) * e;

    if ((t & 63) == 0) {          // true normalize every 64 steps
      float v = wave_sum64(cur);
      if ((j & 63) == 0) red[j >> 6] = v;
      __syncthreads();
      float tot = red[0] + red[1];
      Lacc += __logf(tot);
      cur *= __builtin_amdgcn_rcpf(tot);
    } else if ((t & 3) == 0) {    // exact range bump every 4 steps
      cur *= 0x1p64f;
    }
  }

  float v = wave_sum64(cur);
  if ((j & 63) == 0) red[j >> 6] = v;
  __syncthreads();
  float tot = red[0] + red[1];
  // remove the 480 exact 2^64 factors: 480*64*ln2 = 30720*ln2
  const float RESCALE_C = (float)(30720.0 * 0.6931471805599453);
  if (j == 0) ll[b] = Lacc + __logf(tot) - RESCALE_C;
}

// ---------------- K4: final reduction ----------------
__global__ void k_final(const float* __restrict__ ll, float* __restrict__ out) {
  float v = ll[threadIdx.x];
  v = wave_sum64(v);
  if (threadIdx.x == 0) out[0] = -v;
}

extern "C" void kernel_launch(void* const* d_in, const int* in_sizes, int n_in,
                              void* d_out, int out_size, void* d_ws, size_t ws_size,
                              hipStream_t stream) {
  const int*   toks    = (const int*)d_in[0];
  const float* initlog = (const float*)d_in[1];
  const float* tag     = (const float*)d_in[2];
  const float* word    = (const float*)d_in[3];
  const float* bias    = (const float*)d_in[4];
  const float* q       = (const float*)d_in[5];
  const float* W       = (const float*)d_in[6];
  const float* tb      = (const float*)d_in[7];
  float* out = (float*)d_out;

  const int V = in_sizes[4];          // vocab size (word_bias length)
  const int nPart = (V + 127) / 128;

  float* ws  = (float*)d_ws;
  float* E   = ws;                               // V*K
  float* pZ  = E + (size_t)V * KK;               // nPart*K
  float* A2  = pZ + (size_t)nPart * KK;          // K*K
  float* piZ = A2 + KK * KK;                     // K
  float* ll  = piZ + KK;                         // B

  k_emis <<<nPart, 128, 0, stream>>>(tag, word, bias, E, pZ, V);
  k_trans<<<KK, 128, 0, stream>>>(W, q, tb, pZ, initlog, A2, piZ, nPart);
  k_fwd  <<<BB, 128, 0, stream>>>(toks, E, A2, piZ, ll);
  k_final<<<1, BB, 0, stream>>>(ll, out);
}

// Round 3
// 1454.530 us; speedup vs baseline: 2.3946x; 1.0948x over previous
//
#include <hip/hip_runtime.h>

// Neural HMM forward-algorithm NLL.
// K=128 states, V=50257 vocab, D=H=128, B=64, T=2048.
//
// Pipeline (all fp32, linear-space scaled forward algorithm):
//  K1: E[v][k] = exp(tag[k]·word[v] + bias[v])   (UNNORMALIZED; logits ~ +-0.03
//      so no max-subtraction needed), plus per-block partial Z_k sums.
//  K2: A2[i][j] = softmax_j(W q + b)[i][j] / Z_j  (emission normalizer folded
//      into transition columns), piZ[j] = softmax(init)[j] / Z_j.
//  K3: per-batch recursion a'_j = (sum_i a_i A2_ij) * E[tok]_j.
//      4 waves/block: thread (h,j) holds A2[64h..64h+63][j] in 64 VGPRs
//      (half a column -> no spill; round-2's 128/thread spilled, VGPR=84).
//      Range control: exact *2^64 every 4 steps, true normalize every 64;
//      the 480 exact 2^64 factors removed by compile-time 30720*ln2.
//  K4: out = -sum_b ll[b].

#define KK 128
#define TT 2048
#define BB 64

__device__ __forceinline__ float wave_sum64(float v) {
#pragma unroll
  for (int m = 32; m; m >>= 1) v += __shfl_xor(v, m, 64);
  return v;
}
__device__ __forceinline__ float wave_max64(float v) {
#pragma unroll
  for (int m = 32; m; m >>= 1) v = fmaxf(v, __shfl_xor(v, m, 64));
  return v;
}

// ---------------- K1: emission table E (V x K) + partial Z ----------------
__global__ __launch_bounds__(128, 1)
void k_emis(const float* __restrict__ tag, const float* __restrict__ word,
            const float* __restrict__ bias, float* __restrict__ E,
            float* __restrict__ partialZ, int V) {
  __shared__ float4 wtile[128 * 32];  // 64 KB: 128 vocab rows x 128 d
  __shared__ float btile[128];
  const int tid = threadIdx.x;
  const int v0 = blockIdx.x * 128;

  const float4* w4 = (const float4*)word;
  const int maxi = V * 32 - 1;
#pragma unroll
  for (int it = 0; it < 32; ++it) {
    int idx = it * 128 + tid;
    int g = v0 * 32 + idx;
    wtile[idx] = w4[min(g, maxi)];
  }
  btile[tid] = (v0 + tid < V) ? bias[v0 + tid] : 0.f;

  float treg[128];
  const float4* t4 = (const float4*)(tag + (size_t)tid * 128);
#pragma unroll
  for (int c = 0; c < 32; ++c) {
    float4 x = t4[c];
    treg[4 * c + 0] = x.x; treg[4 * c + 1] = x.y;
    treg[4 * c + 2] = x.z; treg[4 * c + 3] = x.w;
  }
  __syncthreads();

  float zp = 0.f;
  for (int v = 0; v < 128; ++v) {
    if (v0 + v >= V) break;  // uniform
    const float4* row = &wtile[v * 32];
    float a0 = 0.f, a1 = 0.f, a2 = 0.f, a3 = 0.f;
#pragma unroll
    for (int c = 0; c < 32; ++c) {
      float4 pv = row[c];
      a0 = fmaf(pv.x, treg[4 * c + 0], a0);
      a1 = fmaf(pv.y, treg[4 * c + 1], a1);
      a2 = fmaf(pv.z, treg[4 * c + 2], a2);
      a3 = fmaf(pv.w, treg[4 * c + 3], a3);
    }
    float e = __expf((a0 + a1) + (a2 + a3) + btile[v]);
    E[(size_t)(v0 + v) * KK + tid] = e;
    zp += e;
  }
  partialZ[(size_t)blockIdx.x * KK + tid] = zp;  // deterministic (no atomics)
}

// ---------------- K2: transition matrix A2 (K x K) + piZ ----------------
__global__ __launch_bounds__(128)
void k_trans(const float* __restrict__ W, const float* __restrict__ q,
             const float* __restrict__ tb, const float* __restrict__ pZ,
             const float* __restrict__ initlog, float* __restrict__ A2,
             float* __restrict__ piZ, int nPart) {
  __shared__ float qs[KK];
  __shared__ float r0[2], r1[2];
  const int j = threadIdx.x, i = blockIdx.x;
  qs[j] = q[j];
  __syncthreads();

  const float4* w4 = (const float4*)(W + ((size_t)(i * KK + j)) * KK);
  const float4* q4 = (const float4*)qs;
  float a0 = 0.f, a1 = 0.f, a2 = 0.f, a3 = 0.f;
#pragma unroll
  for (int c = 0; c < KK / 4; ++c) {
    float4 wv = w4[c], qv = q4[c];
    a0 = fmaf(wv.x, qv.x, a0); a1 = fmaf(wv.y, qv.y, a1);
    a2 = fmaf(wv.z, qv.z, a2); a3 = fmaf(wv.w, qv.w, a3);
  }
  float logit = (a0 + a1) + (a2 + a3) + tb[i * KK + j];

  float m = wave_max64(logit);
  if ((j & 63) == 0) r0[j >> 6] = m;
  __syncthreads();
  m = fmaxf(r0[0], r0[1]);
  float e = __expf(logit - m);
  float s = wave_sum64(e);
  if ((j & 63) == 0) r1[j >> 6] = s;
  __syncthreads();
  s = r1[0] + r1[1];

  // Z_j: deterministic sum of per-block partials, 8-way ILP (was serial chain)
  float Z0 = 0.f, Z1 = 0.f, Z2 = 0.f, Z3 = 0.f;
  float Z4 = 0.f, Z5 = 0.f, Z6 = 0.f, Z7 = 0.f;
  int p = 0;
  for (; p + 8 <= nPart; p += 8) {
    Z0 += pZ[(size_t)(p + 0) * KK + j]; Z1 += pZ[(size_t)(p + 1) * KK + j];
    Z2 += pZ[(size_t)(p + 2) * KK + j]; Z3 += pZ[(size_t)(p + 3) * KK + j];
    Z4 += pZ[(size_t)(p + 4) * KK + j]; Z5 += pZ[(size_t)(p + 5) * KK + j];
    Z6 += pZ[(size_t)(p + 6) * KK + j]; Z7 += pZ[(size_t)(p + 7) * KK + j];
  }
  for (; p < nPart; ++p) Z0 += pZ[(size_t)p * KK + j];
  float Z = ((Z0 + Z1) + (Z2 + Z3)) + ((Z4 + Z5) + (Z6 + Z7));

  A2[i * KK + j] = e / (s * Z);

  if (i == 0) {
    float x = initlog[j];
    __syncthreads();
    float m2 = wave_max64(x);
    if ((j & 63) == 0) r0[j >> 6] = m2;
    __syncthreads();
    m2 = fmaxf(r0[0], r0[1]);
    float e2 = __expf(x - m2);
    float s2 = wave_sum64(e2);
    if ((j & 63) == 0) r1[j >> 6] = s2;
    __syncthreads();
    s2 = r1[0] + r1[1];
    piZ[j] = e2 / (s2 * Z);
  }
}

// ---------------- K3: forward recursion, one block per batch ----------------
// 256 threads = 4 waves. j = tid&127 (state), h = tid>>7 (row-half).
// Thread (h,j) holds A2[64h + i][j], i=0..63 -> 64 VGPRs, no spill.
__global__ __launch_bounds__(256, 1)
void k_fwd(const int* __restrict__ toks, const float* __restrict__ E,
           const float* __restrict__ A2, const float* __restrict__ piZ,
           float* __restrict__ ll) {
  __shared__ float pb[2][KK];     // alpha double buffer
  __shared__ float part[2 * KK];  // part[2*j+h] half-dot partials
  __shared__ int tk[TT];
  __shared__ float red[4];
  const int tid = threadIdx.x;
  const int j = tid & (KK - 1);
  const int h = tid >> 7;
  const int b = blockIdx.x;

  // stage this batch's tokens (8 KB)
  const int4* t4 = (const int4*)(toks + (size_t)b * TT);
  int4* l4 = (int4*)tk;
#pragma unroll
  for (int c = 0; c < TT / 4 / 256; ++c) l4[c * 256 + tid] = t4[c * 256 + tid];

  // half-column of A -> 64 registers (coalesced: j consecutive per lane)
  float Areg[64];
  {
    const float* Acol = A2 + (size_t)(h * 64) * KK + j;
#pragma unroll
    for (int i = 0; i < 64; ++i) Areg[i] = Acol[i * KK];
  }
  __syncthreads();

  const float* Ej = E + j;
  // E-row prefetch pipeline, 4 deep (L3 latency ~500-900 cyc)
  float eA = Ej[(size_t)tk[1] * KK];
  float eB = Ej[(size_t)tk[2] * KK];
  float eC = Ej[(size_t)tk[3] * KK];
  float eD = Ej[(size_t)tk[4] * KK];
  if (h == 0) pb[0][j] = piZ[j] * Ej[(size_t)tk[0] * KK];
  float Lacc = 0.f;
  __syncthreads();

  for (int t = 1; t < TT; ++t) {
    // phase 1: half-dot (broadcast b128 reads of my p-half + 64 FMAs)
    const float4* ph = (const float4*)&pb[(t - 1) & 1][h * 64];
    float a0 = 0.f, a1 = 0.f, a2 = 0.f, a3 = 0.f;
#pragma unroll
    for (int c = 0; c < 16; ++c) {
      float4 pv = ph[c];
      a0 = fmaf(pv.x, Areg[4 * c + 0], a0);
      a1 = fmaf(pv.y, Areg[4 * c + 1], a1);
      a2 = fmaf(pv.z, Areg[4 * c + 2], a2);
      a3 = fmaf(pv.w, Areg[4 * c + 3], a3);
    }
    part[2 * j + h] = (a0 + a1) + (a2 + a3);
    __syncthreads();  // A: partials visible

    // advance E prefetch (h=0/h=1 duplicate same address: cache-coalesced)
    float e = eA; eA = eB; eB = eC; eC = eD;
    int tn = tk[t + 4 < TT ? t + 4 : TT - 1];
    eD = Ej[(size_t)tn * KK];

    // phase 2: combine halves + emission multiply (h==0 lanes)
    float np = 0.f;
    if (h == 0) {
      float2 pr = *(const float2*)&part[2 * j];  // 2-way bank alias: free
      np = (pr.x + pr.y) * e;
    }
    if ((t & 63) == 0) {  // true normalize every 64 steps
      float v = wave_sum64(np);  // h==1 waves contribute 0
      if ((tid & 63) == 0) red[tid >> 6] = v;
      __syncthreads();  // C
      float tot = (red[0] + red[1]) + (red[2] + red[3]);
      np *= __builtin_amdgcn_rcpf(tot);
      if (tid == 0) Lacc += __logf(tot);
    } else if ((t & 3) == 0) {  // exact range bump every 4 steps
      np *= 0x1p64f;
    }
    if (h == 0) pb[t & 1][j] = np;
    __syncthreads();  // B: new alpha visible
  }

  // final reduction over states
  float lv = (h == 0) ? pb[(TT - 1) & 1][j] : 0.f;
  float v = wave_sum64(lv);
  if ((tid & 63) == 0) red[tid >> 6] = v;
  __syncthreads();
  float tot = (red[0] + red[1]) + (red[2] + red[3]);
  // remove the 480 exact 2^64 factors: 480*64*ln2 = 30720*ln2
  const float RESCALE_C = (float)(30720.0 * 0.6931471805599453);
  if (tid == 0) ll[b] = Lacc + __logf(tot) - RESCALE_C;
}

// ---------------- K4: final reduction ----------------
__global__ void k_final(const float* __restrict__ ll, float* __restrict__ out) {
  float v = ll[threadIdx.x];
  v = wave_sum64(v);
  if (threadIdx.x == 0) out[0] = -v;
}

extern "C" void kernel_launch(void* const* d_in, const int* in_sizes, int n_in,
                              void* d_out, int out_size, void* d_ws, size_t ws_size,
                              hipStream_t stream) {
  const int*   toks    = (const int*)d_in[0];
  const float* initlog = (const float*)d_in[1];
  const float* tag     = (const float*)d_in[2];
  const float* word    = (const float*)d_in[3];
  const float* bias    = (const float*)d_in[4];
  const float* q       = (const float*)d_in[5];
  const float* W       = (const float*)d_in[6];
  const float* tb      = (const float*)d_in[7];
  float* out = (float*)d_out;

  const int V = in_sizes[4];          // vocab size (word_bias length)
  const int nPart = (V + 127) / 128;

  float* ws  = (float*)d_ws;
  float* E   = ws;                               // V*K
  float* pZ  = E + (size_t)V * KK;               // nPart*K
  float* A2  = pZ + (size_t)nPart * KK;          // K*K
  float* piZ = A2 + KK * KK;                     // K
  float* ll  = piZ + KK;                         // B

  k_emis <<<nPart, 128, 0, stream>>>(tag, word, bias, E, pZ, V);
  k_trans<<<KK, 128, 0, stream>>>(W, q, tb, pZ, initlog, A2, piZ, nPart);
  k_fwd  <<<BB, 256, 0, stream>>>(toks, E, A2, piZ, ll);
  k_final<<<1, BB, 0, stream>>>(ll, out);
}

// Round 4
// 1023.749 us; speedup vs baseline: 3.4022x; 1.4208x over previous
//
#include <hip/hip_runtime.h>

// Neural HMM forward-algorithm NLL.  K=128, V=50257, D=H=128, B=64, T=2048.
//
//  K1 k_emis : E[v][k] = exp(tag[k]·word[v] + bias[v]) (unnormalized) + partial Z
//  K2 k_trans: A2[i][j] = softmax_j(Wq+b)[i][j] / Z_j ; piZ[j] = softmax(init)_j / Z_j
//  K3 k_gather: em[t][b][j] = bf16( E[tok[b,t]][j] * bump(t) ),
//               bump(t) = 2^64 if t%4==0 && t%64!=0  (range control folded in)
//  K4 k_fwd_m : MFMA recursion  alpha_t = (alpha_{t-1} · A2) ∘ em_t,
//               true normalize every 64 steps; 4 blocks x 16 batches.
//               D[j][b] = sum_i A2t[j][i] * alphaT[i][b]  via mfma_f32_16x16x32_bf16
//  K5 k_final : out = -sum_b ll[b]

#define KK 128
#define TT 2048
#define BB 64

typedef short v8s __attribute__((ext_vector_type(8)));
typedef float v4f __attribute__((ext_vector_type(4)));

__device__ __forceinline__ float wave_sum64(float v) {
#pragma unroll
  for (int m = 32; m; m >>= 1) v += __shfl_xor(v, m, 64);
  return v;
}
__device__ __forceinline__ float wave_max64(float v) {
#pragma unroll
  for (int m = 32; m; m >>= 1) v = fmaxf(v, __shfl_xor(v, m, 64));
  return v;
}
// f32 -> bf16 round-to-nearest-even (values are positive normals here)
__device__ __forceinline__ unsigned short f2bf(float x) {
  union { float f; unsigned u; } c; c.f = x;
  unsigned r = c.u + 0x7fffu + ((c.u >> 16) & 1u);
  return (unsigned short)(r >> 16);
}
__device__ __forceinline__ float bflo(unsigned u) {
  union { unsigned u; float f; } c; c.u = u << 16; return c.f;
}
__device__ __forceinline__ float bfhi(unsigned u) {
  union { unsigned u; float f; } c; c.u = u & 0xffff0000u; return c.f;
}

// ---------------- K1: emission table E (V x K) + partial Z ----------------
__global__ __launch_bounds__(128, 1)
void k_emis(const float* __restrict__ tag, const float* __restrict__ word,
            const float* __restrict__ bias, float* __restrict__ E,
            float* __restrict__ partialZ, int V) {
  __shared__ float4 wtile[128 * 32];
  __shared__ float btile[128];
  const int tid = threadIdx.x;
  const int v0 = blockIdx.x * 128;

  const float4* w4 = (const float4*)word;
  const int maxi = V * 32 - 1;
#pragma unroll
  for (int it = 0; it < 32; ++it) {
    int idx = it * 128 + tid;
    int g = v0 * 32 + idx;
    wtile[idx] = w4[min(g, maxi)];
  }
  btile[tid] = (v0 + tid < V) ? bias[v0 + tid] : 0.f;

  float treg[128];
  const float4* t4 = (const float4*)(tag + (size_t)tid * 128);
#pragma unroll
  for (int c = 0; c < 32; ++c) {
    float4 x = t4[c];
    treg[4 * c + 0] = x.x; treg[4 * c + 1] = x.y;
    treg[4 * c + 2] = x.z; treg[4 * c + 3] = x.w;
  }
  __syncthreads();

  float zp = 0.f;
  for (int v = 0; v < 128; ++v) {
    if (v0 + v >= V) break;  // uniform
    const float4* row = &wtile[v * 32];
    float a0 = 0.f, a1 = 0.f, a2 = 0.f, a3 = 0.f;
#pragma unroll
    for (int c = 0; c < 32; ++c) {
      float4 pv = row[c];
      a0 = fmaf(pv.x, treg[4 * c + 0], a0);
      a1 = fmaf(pv.y, treg[4 * c + 1], a1);
      a2 = fmaf(pv.z, treg[4 * c + 2], a2);
      a3 = fmaf(pv.w, treg[4 * c + 3], a3);
    }
    float e = __expf((a0 + a1) + (a2 + a3) + btile[v]);
    E[(size_t)(v0 + v) * KK + tid] = e;
    zp += e;
  }
  partialZ[(size_t)blockIdx.x * KK + tid] = zp;
}

// ---------------- K2: transition matrix A2 (K x K) + piZ ----------------
__global__ __launch_bounds__(128)
void k_trans(const float* __restrict__ W, const float* __restrict__ q,
             const float* __restrict__ tb, const float* __restrict__ pZ,
             const float* __restrict__ initlog, float* __restrict__ A2,
             float* __restrict__ piZ, int nPart) {
  __shared__ float qs[KK];
  __shared__ float r0[2], r1[2];
  const int j = threadIdx.x, i = blockIdx.x;
  qs[j] = q[j];
  __syncthreads();

  const float4* w4 = (const float4*)(W + ((size_t)(i * KK + j)) * KK);
  const float4* q4 = (const float4*)qs;
  float a0 = 0.f, a1 = 0.f, a2 = 0.f, a3 = 0.f;
#pragma unroll
  for (int c = 0; c < KK / 4; ++c) {
    float4 wv = w4[c], qv = q4[c];
    a0 = fmaf(wv.x, qv.x, a0); a1 = fmaf(wv.y, qv.y, a1);
    a2 = fmaf(wv.z, qv.z, a2); a3 = fmaf(wv.w, qv.w, a3);
  }
  float logit = (a0 + a1) + (a2 + a3) + tb[i * KK + j];

  float m = wave_max64(logit);
  if ((j & 63) == 0) r0[j >> 6] = m;
  __syncthreads();
  m = fmaxf(r0[0], r0[1]);
  float e = __expf(logit - m);
  float s = wave_sum64(e);
  if ((j & 63) == 0) r1[j >> 6] = s;
  __syncthreads();
  s = r1[0] + r1[1];

  float Z0 = 0.f, Z1 = 0.f, Z2 = 0.f, Z3 = 0.f;
  float Z4 = 0.f, Z5 = 0.f, Z6 = 0.f, Z7 = 0.f;
  int p = 0;
  for (; p + 8 <= nPart; p += 8) {
    Z0 += pZ[(size_t)(p + 0) * KK + j]; Z1 += pZ[(size_t)(p + 1) * KK + j];
    Z2 += pZ[(size_t)(p + 2) * KK + j]; Z3 += pZ[(size_t)(p + 3) * KK + j];
    Z4 += pZ[(size_t)(p + 4) * KK + j]; Z5 += pZ[(size_t)(p + 5) * KK + j];
    Z6 += pZ[(size_t)(p + 6) * KK + j]; Z7 += pZ[(size_t)(p + 7) * KK + j];
  }
  for (; p < nPart; ++p) Z0 += pZ[(size_t)p * KK + j];
  float Z = ((Z0 + Z1) + (Z2 + Z3)) + ((Z4 + Z5) + (Z6 + Z7));

  A2[i * KK + j] = e / (s * Z);

  if (i == 0) {
    float x = initlog[j];
    __syncthreads();
    float m2 = wave_max64(x);
    if ((j & 63) == 0) r0[j >> 6] = m2;
    __syncthreads();
    m2 = fmaxf(r0[0], r0[1]);
    float e2 = __expf(x - m2);
    float s2 = wave_sum64(e2);
    if ((j & 63) == 0) r1[j >> 6] = s2;
    __syncthreads();
    s2 = r1[0] + r1[1];
    piZ[j] = e2 / (s2 * Z);
  }
}

// ---------------- K3: em gather (both sides coalesced) ----------------
// em[t][b][j] as u32 pairs: em_u32[(t*64+b)*64 + j/2] = bf16(j) | bf16(j+1)<<16
__global__ __launch_bounds__(128, 1)
void k_gather(const int* __restrict__ toks, const float* __restrict__ E,
              unsigned* __restrict__ em) {
  const int b = blockIdx.x;        // 0..63
  const int tc = blockIdx.y;       // 0..63 (32 t's each)
  const int lane = threadIdx.x & 63;
  const int half = threadIdx.x >> 6;
  const float2* E2 = (const float2*)E;
#pragma unroll 4
  for (int it = 0; it < 16; ++it) {
    int t = tc * 32 + it * 2 + half;
    int tok = toks[(size_t)b * TT + t];
    float2 v = E2[(size_t)tok * 64 + lane];
    float sc = ((t & 3) == 0 && (t & 63) != 0) ? 0x1p64f : 1.0f;
    unsigned lo = f2bf(v.x * sc), hi = f2bf(v.y * sc);
    em[((size_t)t * BB + b) * 64 + lane] = lo | (hi << 16);
  }
}

// ---------------- K4: MFMA forward recursion ----------------
// 4 blocks x 16 batches. 256 threads = 4 waves, wave w owns j-rows [32w,32w+32).
// D[j][b] = sum_i A2t[j][i] * alpha[b][i]:
//   A-operand (A2t, static, regs): lane: row j = jt*16 + (l&15), k i = (l>>4)*8+e
//   B-operand (alpha, LDS)       : lane: col b = l&15,          k i = (l>>4)*8+e
//   C/D: col b = l&15, row j = jt*16 + (l>>4)*4 + r   [guide §3, m89-verified]
// alpha LDS rows XOR-swizzled (16B chunk c -> c ^ (b&15)) for conflict-free
// ds_read_b128 / ds_write_b64.
__global__ __launch_bounds__(256, 1)
void k_fwd_m(const unsigned* __restrict__ em, const float* __restrict__ A2,
             const float* __restrict__ piZ, float* __restrict__ ll) {
  __shared__ __align__(16) unsigned short alds[2][16 * KK];  // 2 x 4KB bf16
  __shared__ float red[4][16];
  const int tid = threadIdx.x;
  const int w = tid >> 6;
  const int l = tid & 63;
  const int b = l & 15;
  const int g = l >> 4;
  const int bblk = blockIdx.x;

  // ---- static A2^T fragments: q in {0,1}, jt = 2w+q, kc in 0..3 ----
  v8s a2f[2][4];
#pragma unroll
  for (int q = 0; q < 2; ++q) {
    int j = (2 * w + q) * 16 + b;
#pragma unroll
    for (int kc = 0; kc < 4; ++kc) {
      v8s f;
#pragma unroll
      for (int e = 0; e < 8; ++e)
        f[e] = (short)f2bf(A2[(kc * 32 + g * 8 + e) * KK + j]);
      a2f[q][kc] = f;
    }
  }

  // em addressing: row of global batch (bblk*16+b); u32 stride 4096 per t
  const unsigned* emL = em + (size_t)(bblk * 16 + b) * 64;
  const int joff0 = (2 * w + 0) * 8 + g * 2;  // u32 offset of j-quad, q=0
  const int joff1 = (2 * w + 1) * 8 + g * 2;

  // swizzled LDS addresses (byte offsets within a 256B row)
  // write: 4 consecutive bf16 at byteoff = 32*jt + 8*g
  const int wb0 = 32 * (2 * w + 0) + 8 * g;
  const int wb1 = 32 * (2 * w + 1) + 8 * g;
  const int wswz0 = b * 256 + ((((wb0 >> 4) ^ b) << 4) | (wb0 & 15));
  const int wswz1 = b * 256 + ((((wb1 >> 4) ^ b) << 4) | (wb1 & 15));

  // ---- init alpha0 = piZ * em[0] ----
  float n00, n01, n02, n03, n10, n11, n12, n13;
  {
    uint2 e0 = *(const uint2*)(emL + joff0);
    uint2 e1 = *(const uint2*)(emL + joff1);
    float4 pz0 = *(const float4*)(piZ + (2 * w + 0) * 16 + g * 4);
    float4 pz1 = *(const float4*)(piZ + (2 * w + 1) * 16 + g * 4);
    n00 = pz0.x * bflo(e0.x); n01 = pz0.y * bfhi(e0.x);
    n02 = pz0.z * bflo(e0.y); n03 = pz0.w * bfhi(e0.y);
    n10 = pz1.x * bflo(e1.x); n11 = pz1.y * bfhi(e1.x);
    n12 = pz1.z * bflo(e1.y); n13 = pz1.w * bfhi(e1.y);
    *(uint2*)((char*)alds[0] + wswz0) =
        make_uint2(f2bf(n00) | ((unsigned)f2bf(n01) << 16),
                   f2bf(n02) | ((unsigned)f2bf(n03) << 16));
    *(uint2*)((char*)alds[0] + wswz1) =
        make_uint2(f2bf(n10) | ((unsigned)f2bf(n11) << 16),
                   f2bf(n12) | ((unsigned)f2bf(n13) << 16));
  }

  // em register prefetch pipeline, depth 3 (named regs; no runtime indexing)
  uint2 eA0 = *(const uint2*)(emL + (size_t)1 * 4096 + joff0);
  uint2 eA1 = *(const uint2*)(emL + (size_t)1 * 4096 + joff1);
  uint2 eB0 = *(const uint2*)(emL + (size_t)2 * 4096 + joff0);
  uint2 eB1 = *(const uint2*)(emL + (size_t)2 * 4096 + joff1);
  uint2 eC0 = *(const uint2*)(emL + (size_t)3 * 4096 + joff0);
  uint2 eC1 = *(const uint2*)(emL + (size_t)3 * 4096 + joff1);

  float Lacc = 0.f;
  __syncthreads();

  for (int t = 1; t < TT; ++t) {
    const unsigned short* cur = alds[(t - 1) & 1];
    unsigned short* nxt = alds[t & 1];

    // B-fragments (alpha) + MFMA, accumulate over kc
    v4f acc0 = {0.f, 0.f, 0.f, 0.f}, acc1 = {0.f, 0.f, 0.f, 0.f};
#pragma unroll
    for (int kc = 0; kc < 4; ++kc) {
      v8s bf_ = *(const v8s*)((const char*)cur + b * 256 +
                              ((((kc * 4 + g)) ^ b) << 4));
      acc0 = __builtin_amdgcn_mfma_f32_16x16x32_bf16(a2f[0][kc], bf_, acc0, 0, 0, 0);
      acc1 = __builtin_amdgcn_mfma_f32_16x16x32_bf16(a2f[1][kc], bf_, acc1, 0, 0, 0);
    }

    // rotate em pipeline, prefetch t+3
    uint2 e0 = eA0, e1 = eA1;
    eA0 = eB0; eA1 = eB1; eB0 = eC0; eB1 = eC1;
    {
      int tp = (t + 3 < TT) ? t + 3 : TT - 1;
      eC0 = *(const uint2*)(emL + (size_t)tp * 4096 + joff0);
      eC1 = *(const uint2*)(emL + (size_t)tp * 4096 + joff1);
    }

    // epilogue: multiply by emission (bump pre-folded into em)
    n00 = acc0[0] * bflo(e0.x); n01 = acc0[1] * bfhi(e0.x);
    n02 = acc0[2] * bflo(e0.y); n03 = acc0[3] * bfhi(e0.y);
    n10 = acc1[0] * bflo(e1.x); n11 = acc1[1] * bfhi(e1.x);
    n12 = acc1[2] * bflo(e1.y); n13 = acc1[3] * bfhi(e1.y);

    if ((t & 63) == 0) {  // true normalize (uniform branch)
      float ps = ((n00 + n01) + (n02 + n03)) + ((n10 + n11) + (n12 + n13));
      ps += __shfl_xor(ps, 16, 64);
      ps += __shfl_xor(ps, 32, 64);
      if (l < 16) red[w][l] = ps;
      __syncthreads();
      float tot = (red[0][b] + red[1][b]) + (red[2][b] + red[3][b]);
      float rc = __builtin_amdgcn_rcpf(tot);
      n00 *= rc; n01 *= rc; n02 *= rc; n03 *= rc;
      n10 *= rc; n11 *= rc; n12 *= rc; n13 *= rc;
      Lacc += __logf(tot);
    }

    *(uint2*)((char*)nxt + wswz0) =
        make_uint2(f2bf(n00) | ((unsigned)f2bf(n01) << 16),
                   f2bf(n02) | ((unsigned)f2bf(n03) << 16));
    *(uint2*)((char*)nxt + wswz1) =
        make_uint2(f2bf(n10) | ((unsigned)f2bf(n11) << 16),
                   f2bf(n12) | ((unsigned)f2bf(n13) << 16));
    __syncthreads();
  }

  // final: n* hold alpha_{T-1}
  float ps = ((n00 + n01) + (n02 + n03)) + ((n10 + n11) + (n12 + n13));
  ps += __shfl_xor(ps, 16, 64);
  ps += __shfl_xor(ps, 32, 64);
  if (l < 16) red[w][l] = ps;
  __syncthreads();
  if (w == 0 && l < 16) {
    float tot = (red[0][l] + red[1][l]) + (red[2][l] + red[3][l]);
    // remove 480 folded 2^64 bumps: 480*64*ln2
    const float RESCALE_C = (float)(30720.0 * 0.6931471805599453);
    ll[bblk * 16 + l] = Lacc + __logf(tot) - RESCALE_C;
  }
}

// ---------------- K4-fallback (round-3 path, used if ws too small) --------
__global__ __launch_bounds__(256, 1)
void k_fwd_fb(const int* __restrict__ toks, const float* __restrict__ E,
              const float* __restrict__ A2, const float* __restrict__ piZ,
              float* __restrict__ ll) {
  __shared__ float pb[2][KK];
  __shared__ float part[2 * KK];
  __shared__ int tk[TT];
  __shared__ float red[4];
  const int tid = threadIdx.x;
  const int j = tid & (KK - 1);
  const int h = tid >> 7;
  const int b = blockIdx.x;

  const int4* t4 = (const int4*)(toks + (size_t)b * TT);
  int4* l4 = (int4*)tk;
#pragma unroll
  for (int c = 0; c < TT / 4 / 256; ++c) l4[c * 256 + tid] = t4[c * 256 + tid];

  float Areg[64];
  {
    const float* Acol = A2 + (size_t)(h * 64) * KK + j;
#pragma unroll
    for (int i = 0; i < 64; ++i) Areg[i] = Acol[i * KK];
  }
  __syncthreads();

  const float* Ej = E + j;
  float eA = Ej[(size_t)tk[1] * KK];
  float eB = Ej[(size_t)tk[2] * KK];
  float eC = Ej[(size_t)tk[3] * KK];
  float eD = Ej[(size_t)tk[4] * KK];
  if (h == 0) pb[0][j] = piZ[j] * Ej[(size_t)tk[0] * KK];
  float Lacc = 0.f;
  __syncthreads();

  for (int t = 1; t < TT; ++t) {
    const float4* ph = (const float4*)&pb[(t - 1) & 1][h * 64];
    float a0 = 0.f, a1 = 0.f, a2 = 0.f, a3 = 0.f;
#pragma unroll
    for (int c = 0; c < 16; ++c) {
      float4 pv = ph[c];
      a0 = fmaf(pv.x, Areg[4 * c + 0], a0);
      a1 = fmaf(pv.y, Areg[4 * c + 1], a1);
      a2 = fmaf(pv.z, Areg[4 * c + 2], a2);
      a3 = fmaf(pv.w, Areg[4 * c + 3], a3);
    }
    part[2 * j + h] = (a0 + a1) + (a2 + a3);
    __syncthreads();

    float e = eA; eA = eB; eB = eC; eC = eD;
    int tn = tk[t + 4 < TT ? t + 4 : TT - 1];
    eD = Ej[(size_t)tn * KK];

    float np = 0.f;
    if (h == 0) {
      float2 pr = *(const float2*)&part[2 * j];
      np = (pr.x + pr.y) * e;
    }
    if ((t & 63) == 0) {
      float v = wave_sum64(np);
      if ((tid & 63) == 0) red[tid >> 6] = v;
      __syncthreads();
      float tot = (red[0] + red[1]) + (red[2] + red[3]);
      np *= __builtin_amdgcn_rcpf(tot);
      if (tid == 0) Lacc += __logf(tot);
    } else if ((t & 3) == 0) {
      np *= 0x1p64f;
    }
    if (h == 0) pb[t & 1][j] = np;
    __syncthreads();
  }

  float lv = (h == 0) ? pb[(TT - 1) & 1][j] : 0.f;
  float v = wave_sum64(lv);
  if ((tid & 63) == 0) red[tid >> 6] = v;
  __syncthreads();
  float tot = (red[0] + red[1]) + (red[2] + red[3]);
  const float RESCALE_C = (float)(30720.0 * 0.6931471805599453);
  if (tid == 0) ll[b] = Lacc + __logf(tot) - RESCALE_C;
}

// ---------------- K5: final reduction ----------------
__global__ void k_final(const float* __restrict__ ll, float* __restrict__ out) {
  float v = ll[threadIdx.x];
  v = wave_sum64(v);
  if (threadIdx.x == 0) out[0] = -v;
}

extern "C" void kernel_launch(void* const* d_in, const int* in_sizes, int n_in,
                              void* d_out, int out_size, void* d_ws, size_t ws_size,
                              hipStream_t stream) {
  const int*   toks    = (const int*)d_in[0];
  const float* initlog = (const float*)d_in[1];
  const float* tag     = (const float*)d_in[2];
  const float* word    = (const float*)d_in[3];
  const float* bias    = (const float*)d_in[4];
  const float* q       = (const float*)d_in[5];
  const float* W       = (const float*)d_in[6];
  const float* tb      = (const float*)d_in[7];
  float* out = (float*)d_out;

  const int V = in_sizes[4];
  const int nPart = (V + 127) / 128;

  float* ws  = (float*)d_ws;
  float* E   = ws;
  float* pZ  = E + (size_t)V * KK;
  float* A2  = pZ + (size_t)nPart * KK;
  float* piZ = A2 + KK * KK;
  float* ll  = piZ + KK;
  unsigned* em = (unsigned*)(ll + BB);  // TT*BB*64 u32 = 32 MB

  const size_t floats_before_em =
      (size_t)V * KK + (size_t)nPart * KK + KK * KK + KK + BB;
  const size_t need = floats_before_em * 4 + (size_t)TT * BB * 64 * 4;

  k_emis <<<nPart, 128, 0, stream>>>(tag, word, bias, E, pZ, V);
  k_trans<<<KK, 128, 0, stream>>>(W, q, tb, pZ, initlog, A2, piZ, nPart);
  if (ws_size >= need) {
    k_gather<<<dim3(BB, TT / 32), 128, 0, stream>>>(toks, E, em);
    k_fwd_m <<<4, 256, 0, stream>>>(em, A2, piZ, ll);
  } else {
    k_fwd_fb<<<BB, 256, 0, stream>>>(toks, E, A2, piZ, ll);
  }
  k_final<<<1, BB, 0, stream>>>(ll, out);
}